// Round 1
// baseline (220.074 us; speedup 1.0000x reference)
//
#include <hip/hip_runtime.h>
#include <stdint.h>
#include <math.h>

// Problem constants (B=8192 rows, D=512 features)
#define Bn 8192
#define Dn 512
#define EPSN 1e-12f
#define EPSP 1e-6f
#define MARG 0.3f

#define BM 128
#define BN 128
#define BK 32
#define NCT (Bn / BN)   // 64 column tiles

typedef short bf16x8 __attribute__((ext_vector_type(8)));  // 8 bf16 (4 VGPRs)
typedef float f32x4  __attribute__((ext_vector_type(4)));

__device__ __forceinline__ uint16_t f2bf(float f) {
    union { float f; uint32_t u; } c; c.f = f;
    uint32_t r = (c.u + 0x7fffu + ((c.u >> 16) & 1u)) >> 16;  // RNE
    return (uint16_t)r;
}

// async global->LDS, 16B per lane; LDS dest must be wave-uniform base + lane*16
__device__ __forceinline__ void async16(const void* g, void* l) {
    __builtin_amdgcn_global_load_lds(
        (const __attribute__((address_space(1))) void*)g,
        (__attribute__((address_space(3))) void*)l,
        16, 0, 0);
}

// ---------------------------------------------------------------------------
// K1: per-row L2 normalize (fp32 out + bf16 out), per-p-row column term
// c[j] = -sp2[j] + 2*eps*sp[j]  (the j-varying part of sim besides 2*dot)
// One wave per 512-float row; 16384 rows total (a and p interleaved).
// ---------------------------------------------------------------------------
__global__ __launch_bounds__(256) void k_normalize(
    const float* __restrict__ x,
    float* __restrict__ a_n, float* __restrict__ p_n,
    uint16_t* __restrict__ a_bf, uint16_t* __restrict__ p_bf,
    float* __restrict__ cterm)
{
    const int wave = threadIdx.x >> 6;
    const int lane = threadIdx.x & 63;
    const int r = blockIdx.x * 4 + wave;   // 0..16383
    const int i = r >> 1;
    const int which = r & 1;               // 0 = a-row, 1 = p-row

    const float* src = x + (size_t)i * (2 * Dn) + (size_t)which * Dn + lane * 8;
    float4 lo = ((const float4*)src)[0];
    float4 hi = ((const float4*)src)[1];
    float v[8] = {lo.x, lo.y, lo.z, lo.w, hi.x, hi.y, hi.z, hi.w};

    float ss = 0.f;
#pragma unroll
    for (int j = 0; j < 8; ++j) ss += v[j] * v[j];
#pragma unroll
    for (int m = 1; m < 64; m <<= 1) ss += __shfl_xor(ss, m);
    const float scale = 1.0f / fmaxf(sqrtf(ss), EPSN);

    float s1 = 0.f, s2 = 0.f;
    float o[8];
#pragma unroll
    for (int j = 0; j < 8; ++j) { o[j] = v[j] * scale; s1 += o[j]; s2 += o[j] * o[j]; }

    float* dst = (which ? p_n : a_n) + (size_t)i * Dn + lane * 8;
    ((float4*)dst)[0] = make_float4(o[0], o[1], o[2], o[3]);
    ((float4*)dst)[1] = make_float4(o[4], o[5], o[6], o[7]);

    uint16_t* bdst = (which ? p_bf : a_bf) + (size_t)i * Dn + lane * 8;
    bf16x8 bb;
#pragma unroll
    for (int j = 0; j < 8; ++j) bb[j] = (short)f2bf(o[j]);
    *(bf16x8*)bdst = bb;

    if (which) {
#pragma unroll
        for (int m = 1; m < 64; m <<= 1) { s1 += __shfl_xor(s1, m); s2 += __shfl_xor(s2, m); }
        if (lane == 0) cterm[i] = -s2 + 2.0f * EPSP * s1;
    }
}

// ---------------------------------------------------------------------------
// K2: bf16 MFMA GEMM (a_n @ p_n^T) with fused per-row argmax over the 128-col
// tile. Writes per-(row, colTile) partial (maxval, argidx).
// m97 structure: 128x128 tile, BK=32, 4 waves in 2x2, each wave 4x4 MFMAs.
// ---------------------------------------------------------------------------
__global__ __launch_bounds__(256) void k_gemm_argmax(
    const uint16_t* __restrict__ a_bf, const uint16_t* __restrict__ p_bf,
    const float* __restrict__ cterm,
    float* __restrict__ pval, int* __restrict__ pidx)
{
    __shared__ uint16_t As[BM * BK];   // 8 KB, row-major [row][32]
    __shared__ uint16_t Bs[BN * BK];   // 8 KB, row-major [prow][32]
    __shared__ float rv[2][BM];
    __shared__ int   ri[2][BM];

    const int t = threadIdx.x;
    const int wave = t >> 6;
    const int lane = t & 63;
    const int rowBase = blockIdx.y * BM;
    const int colBase = blockIdx.x * BN;

    f32x4 acc[4][4];
#pragma unroll
    for (int a = 0; a < 4; ++a)
#pragma unroll
        for (int b = 0; b < 4; ++b) acc[a][b] = (f32x4){0.f, 0.f, 0.f, 0.f};

    const int q = lane >> 4;       // 0..3
    const int m16 = lane & 15;     // 0..15
    const int waveRow = (wave >> 1) * 64;
    const int waveCol = (wave & 1) * 64;

    for (int kt = 0; kt < Dn / BK; ++kt) {
        const int k0 = kt * BK;
        // --- stage A and B tiles: 512 chunks of 16B each, 2 per thread per tile
#pragma unroll
        for (int s = 0; s < 2; ++s) {
            const int c = s * 256 + t;
            const int row = c >> 2;        // 0..127
            const int kc = c & 3;          // 16B chunk within 64B row
            const uint16_t* ga = a_bf + (size_t)(rowBase + row) * Dn + k0 + kc * 8;
            const uint16_t* gb = p_bf + (size_t)(colBase + row) * Dn + k0 + kc * 8;
            // wave-uniform LDS base: chunk index (s*256 + wave*64) -> *16 bytes
            uint16_t* la = As + (size_t)(s * 256 + wave * 64) * 8;
            uint16_t* lb = Bs + (size_t)(s * 256 + wave * 64) * 8;
            async16(ga, la);
            async16(gb, lb);
        }
        __syncthreads();   // drains vmcnt (global_load_lds) + barrier

        // --- fragments + MFMA
        bf16x8 af[4], bfr[4];
#pragma unroll
        for (int mt = 0; mt < 4; ++mt) {
            const int r = waveRow + mt * 16 + m16;            // A row m = lane&15
            af[mt] = *(const bf16x8*)(As + r * BK + q * 8);   // k = q*8 + j
        }
#pragma unroll
        for (int nt = 0; nt < 4; ++nt) {
            const int r = waveCol + nt * 16 + m16;            // B col n = lane&15
            bfr[nt] = *(const bf16x8*)(Bs + r * BK + q * 8);
        }
#pragma unroll
        for (int mt = 0; mt < 4; ++mt)
#pragma unroll
            for (int nt = 0; nt < 4; ++nt)
                acc[mt][nt] = __builtin_amdgcn_mfma_f32_16x16x32_bf16(
                    af[mt], bfr[nt], acc[mt][nt], 0, 0, 0);
        __syncthreads();   // before next tile overwrites LDS
    }

    // --- epilogue: score = 2*dot + c[j]; mask diagonal; per-row argmax over tile
    float cv[4];
#pragma unroll
    for (int nt = 0; nt < 4; ++nt)
        cv[nt] = cterm[colBase + waveCol + nt * 16 + m16];

#pragma unroll
    for (int mt = 0; mt < 4; ++mt) {
#pragma unroll
        for (int v = 0; v < 4; ++v) {
            const int lr = waveRow + mt * 16 + q * 4 + v;   // C/D row = quad*4+reg
            const int gi = rowBase + lr;
            float best = -INFINITY;
            int bidx = 0x7fffffff;
#pragma unroll
            for (int nt = 0; nt < 4; ++nt) {
                const int gj = colBase + waveCol + nt * 16 + m16;  // C/D col = lane&15
                float sc = 2.0f * acc[mt][nt][v] + cv[nt];
                if (gj == gi) sc = -INFINITY;
                if (sc > best || (sc == best && gj < bidx)) { best = sc; bidx = gj; }
            }
            // reduce across the 16 lanes of this quad-group (first-index tiebreak)
#pragma unroll
            for (int msk = 1; msk < 16; msk <<= 1) {
                float ob = __shfl_xor(best, msk);
                int oi = __shfl_xor(bidx, msk);
                if (ob > best || (ob == best && oi < bidx)) { best = ob; bidx = oi; }
            }
            if (m16 == 0) { rv[wave & 1][lr] = best; ri[wave & 1][lr] = bidx; }
        }
    }
    __syncthreads();
    if (t < BM) {
        float b0 = rv[0][t]; int i0 = ri[0][t];
        float b1 = rv[1][t]; int i1 = ri[1][t];
        if (b1 > b0 || (b1 == b0 && i1 < i0)) { b0 = b1; i0 = i1; }
        const size_t o = (size_t)(rowBase + t) * NCT + blockIdx.x;
        pval[o] = b0;
        pidx[o] = i0;
    }
}

// ---------------------------------------------------------------------------
// K3: reduce 64 partials -> negidx; compute pos_d^2 / neg_d^2 in fp32 exactly
// as the reference (elementwise a - p + eps), relu margin per row.
// One wave per row.
// ---------------------------------------------------------------------------
__global__ __launch_bounds__(256) void k_rowloss(
    const float* __restrict__ a_n, const float* __restrict__ p_n,
    const float* __restrict__ pval, const int* __restrict__ pidx,
    float* __restrict__ rowloss)
{
    const int wave = threadIdx.x >> 6;
    const int lane = threadIdx.x & 63;
    const int i = blockIdx.x * 4 + wave;

    float best = pval[(size_t)i * NCT + lane];
    int bidx = pidx[(size_t)i * NCT + lane];
#pragma unroll
    for (int msk = 1; msk < 64; msk <<= 1) {
        float ob = __shfl_xor(best, msk);
        int oi = __shfl_xor(bidx, msk);
        if (ob > best || (ob == best && oi < bidx)) { best = ob; bidx = oi; }
    }

    const float4* av = (const float4*)(a_n + (size_t)i * Dn);
    const float4* pv = (const float4*)(p_n + (size_t)i * Dn);
    const float4* nv = (const float4*)(p_n + (size_t)bidx * Dn);
    float pos = 0.f, ng = 0.f;
#pragma unroll
    for (int c = 0; c < 2; ++c) {
        const int idx = lane + c * 64;
        float4 a4 = av[idx], p4 = pv[idx], n4 = nv[idx];
        float u;
        u = a4.x - p4.x + EPSP; pos += u * u;
        u = a4.y - p4.y + EPSP; pos += u * u;
        u = a4.z - p4.z + EPSP; pos += u * u;
        u = a4.w - p4.w + EPSP; pos += u * u;
        u = a4.x - n4.x + EPSP; ng += u * u;
        u = a4.y - n4.y + EPSP; ng += u * u;
        u = a4.z - n4.z + EPSP; ng += u * u;
        u = a4.w - n4.w + EPSP; ng += u * u;
    }
#pragma unroll
    for (int msk = 1; msk < 64; msk <<= 1) {
        pos += __shfl_xor(pos, msk);
        ng += __shfl_xor(ng, msk);
    }
    if (lane == 0) rowloss[i] = fmaxf(pos - ng + MARG, 0.f);
}

// ---------------------------------------------------------------------------
// K4: mean over 8192 row losses -> scalar out (deterministic, no atomics)
// ---------------------------------------------------------------------------
__global__ __launch_bounds__(256) void k_final(
    const float* __restrict__ rowloss, float* __restrict__ out)
{
    __shared__ float sm[4];
    float s = 0.f;
    for (int k = threadIdx.x; k < Bn; k += 256) s += rowloss[k];
#pragma unroll
    for (int msk = 1; msk < 64; msk <<= 1) s += __shfl_xor(s, msk);
    if ((threadIdx.x & 63) == 0) sm[threadIdx.x >> 6] = s;
    __syncthreads();
    if (threadIdx.x == 0) out[0] = (sm[0] + sm[1] + sm[2] + sm[3]) * (1.0f / Bn);
}

extern "C" void kernel_launch(void* const* d_in, const int* in_sizes, int n_in,
                              void* d_out, int out_size, void* d_ws, size_t ws_size,
                              hipStream_t stream)
{
    const float* x = (const float*)d_in[0];
    char* ws = (char*)d_ws;
    // workspace layout (bytes):
    float*    a_n     = (float*)(ws + 0);           // 16 MB
    float*    p_n     = (float*)(ws + 16777216);    // 16 MB
    uint16_t* a_bf    = (uint16_t*)(ws + 33554432); //  8 MB
    uint16_t* p_bf    = (uint16_t*)(ws + 41943040); //  8 MB
    float*    cterm   = (float*)(ws + 50331648);    // 32 KB
    float*    pval    = (float*)(ws + 50364416);    //  2 MB
    int*      pidx    = (int*)(ws + 52461568);      //  2 MB
    float*    rowloss = (float*)(ws + 54558720);    // 32 KB   (total ~52.1 MB)
    float*    out     = (float*)d_out;

    k_normalize<<<4096, 256, 0, stream>>>(x, a_n, p_n, a_bf, p_bf, cterm);
    k_gemm_argmax<<<dim3(NCT, Bn / BM), 256, 0, stream>>>(a_bf, p_bf, cterm, pval, pidx);
    k_rowloss<<<2048, 256, 0, stream>>>(a_n, p_n, pval, pidx, rowloss);
    k_final<<<1, 256, 0, stream>>>(rowloss, out);
}